// Round 4
// baseline (169.263 us; speedup 1.0000x reference)
//
#include <hip/hip_runtime.h>
#include <math.h>

#define NT 1024
#define NW 16

// Kernel 1: grid 512 = (bt, half). half0 -> thetas {0,1,2}, half1 -> {3,4}.
// 16 waves; lane = channel hh; each wave owns ONE strip of 9 consecutive
// shifts per theta. Best-sim tracked as (pnum = d*|d|, pden = ss) pairs,
// compared by cross-multiplication (monotone in sim, tie-exact).
__global__ __launch_bounds__(NT, 8) void argaug_scan(
    const float* __restrict__ x, const float* __restrict__ y,
    const int* __restrict__ mask,
    const float* __restrict__ W1, const float* __restrict__ b1,
    const float* __restrict__ W2, const float* __restrict__ b2,
    double* __restrict__ outN, double* __restrict__ outD,
    int* __restrict__ outS, int* __restrict__ outT)
{
    __shared__ float  sW2[4096];       // W2[o][h] row-major
    __shared__ double wdBuf[76 * 64];  // f64 window values wd[j][h]; aliased by rsim/ridx
    __shared__ double ypad[80];        // ypad[p] = y[p-8] for p in [8,71], else 0
    __shared__ float  sx[64], sy[64], sh[64], sb1[64], sb2[64];
    __shared__ double bestN[64], bestD[64];
    __shared__ int    bestS[64], bestT[64];

    double* rsimN = wdBuf;                      // [NW*64] (aliased, barrier-separated)
    double* rsimD = wdBuf + NW * 64;            // [NW*64]
    int*    ridxB = (int*)(wdBuf + 2 * NW * 64);

    const int tid  = threadIdx.x;
    const int bx   = blockIdx.x;
    const int bt   = bx & 255;
    const int half = bx >> 8;
    const int hh   = tid & 63;
    const int sg   = tid >> 6;

    for (int k = tid; k < 4096; k += NT) sW2[k] = W2[k];
    if (tid < 64) {
        sx[tid]  = x[bt * 64 + tid];
        sy[tid]  = y[bt * 64 + tid];
        sb1[tid] = b1[tid];
        sb2[tid] = b2[tid];
    }
    __syncthreads();

    if (tid < 64) {
        float acc = 0.0f;
        const float* w1r = W1 + tid * 64;
        for (int i = 0; i < 64; ++i) acc = fmaf(sx[i], w1r[i], acc);
        acc += sb1[tid];
        sh[tid] = acc * (float)mask[bt * 64 + tid];
        bestN[tid] = -1.0; bestD[tid] = 0.0;
        bestS[tid] = 0;    bestT[tid] = 0;
    } else if (tid >= 128 && tid < 208) {
        const int p = tid - 128;
        ypad[p] = (p >= 8 && p < 72) ? (double)sy[p - 8] : 0.0;
    }
    __syncthreads();

    const int t5beg = half ? 3 : 0;
    const int t5end = half ? 5 : 3;

    for (int t5 = t5beg; t5 < t5end; ++t5) {
        const double theta = (t5 == 4) ? 1.2 : (0.8 + (double)t5 * ((1.2 - 0.8) / 4.0));
        const int L = (int)floor(64.0 * theta);   // {51,57,64,70,76}
        const int S = L + 63;
        const double rcp = 64.0 / (double)L;

        // Phase A (parallel): wd[j][h] = (f64)(sh[h]*W2[src(j)][h] + b2[src(j)])
        for (int k = tid; k < L * 64; k += NT) {
            const int j = k >> 6, h = k & 63;     // j wave-uniform
            int sj = (int)floor((double)j * rcp);
            if (sj > 63) sj = 63;
            const float wf = sh[h] * sW2[sj * 64 + h] + sb2[sj];
            wdBuf[k] = (double)wf;
        }
        __syncthreads();

        double bN = -1.0, bD = 0.0; int bi = 0x7fffffff;
        const int s_first = 9 * sg;
        if (s_first < S) {
            const int jstart = (s_first > 63) ? (s_first - 63) : 0;
            const int jmid   = (s_first < L - 1) ? s_first : (L - 1);
            const int jend   = (s_first + 8 < L - 1) ? (s_first + 8) : (L - 1);
            const int C      = 71 - s_first;      // ypad idx = j + C - k

            double d0=0,d1=0,d2=0,d3=0,d4=0,d5=0,d6=0,d7=0,d8=0,ssA=0;
            double ym1 = ypad[jstart + C - 1];
            double ym2 = ypad[jstart + C - 2];
            double ym3 = ypad[jstart + C - 3];
            double ym4 = ypad[jstart + C - 4];
            double ym5 = ypad[jstart + C - 5];
            double ym6 = ypad[jstart + C - 6];
            double ym7 = ypad[jstart + C - 7];
            double ym8 = ypad[jstart + C - 8];

            #pragma unroll 9
            for (int j = jstart; j <= jmid; ++j) {
                const double w  = wdBuf[j * 64 + hh];
                const double y0 = ypad[j + C];
                d0 = fma(w, y0,  d0); d1 = fma(w, ym1, d1); d2 = fma(w, ym2, d2);
                d3 = fma(w, ym3, d3); d4 = fma(w, ym4, d4); d5 = fma(w, ym5, d5);
                d6 = fma(w, ym6, d6); d7 = fma(w, ym7, d7); d8 = fma(w, ym8, d8);
                ssA = fma(w, w, ssA);
                ym8=ym7; ym7=ym6; ym6=ym5; ym5=ym4; ym4=ym3; ym3=ym2; ym2=ym1; ym1=y0;
            }
            #pragma unroll 9
            for (int j = jmid + 1; j <= jend; ++j) {
                const double w  = wdBuf[j * 64 + hh];
                const double y0 = ypad[j + C];
                d0 = fma(w, y0,  d0); d1 = fma(w, ym1, d1); d2 = fma(w, ym2, d2);
                d3 = fma(w, ym3, d3); d4 = fma(w, ym4, d4); d5 = fma(w, ym5, d5);
                d6 = fma(w, ym6, d6); d7 = fma(w, ym7, d7); d8 = fma(w, ym8, d8);
                ym8=ym7; ym7=ym6; ym6=ym5; ym5=ym4; ym4=ym3; ym3=ym2; ym2=ym1; ym1=y0;
            }

            const int kmax = (S - s_first < 9) ? (S - s_first) : 9;
            double ss = ssA;
            #define SSUP(kk) { \
                const int jh = s_first + kk; \
                const int jl = s_first + kk - 64; \
                if (jh <= L - 1) { const double w = wdBuf[jh * 64 + hh]; ss = fma(w,  w, ss); } \
                if (jl >= 0)     { const double w = wdBuf[jl * 64 + hh]; ss = fma(-w, w, ss); } }
            #define EVALK(kk, dk) { \
                double pn, pd; \
                if (ss > 0.0) { pn = dk * fabs(dk); pd = ss; } \
                else          { pn = 0.0;           pd = 1.0; } \
                if (pn * bD > bN * pd) { bN = pn; bD = pd; bi = s_first + kk; } }
            EVALK(0, d0)
            if (1 < kmax) { SSUP(1) EVALK(1, d1) }
            if (2 < kmax) { SSUP(2) EVALK(2, d2) }
            if (3 < kmax) { SSUP(3) EVALK(3, d3) }
            if (4 < kmax) { SSUP(4) EVALK(4, d4) }
            if (5 < kmax) { SSUP(5) EVALK(5, d5) }
            if (6 < kmax) { SSUP(6) EVALK(6, d6) }
            if (7 < kmax) { SSUP(7) EVALK(7, d7) }
            if (8 < kmax) { SSUP(8) EVALK(8, d8) }
            #undef SSUP
            #undef EVALK
        }
        __syncthreads();                 // wdBuf reads complete before alias writes
        rsimN[sg * 64 + hh] = bN;
        rsimD[sg * 64 + hh] = bD;
        ridxB[sg * 64 + hh] = bi;
        __syncthreads();
        if (tid < 64) {
            double mN = -1.0, mD = 0.0; int mi = 0;
            for (int g = 0; g < NW; ++g) {       // ascending s: strict > keeps first max
                const double vN = rsimN[g * 64 + tid];
                const double vD = rsimD[g * 64 + tid];
                if (vN * mD > mN * vD) { mN = vN; mD = vD; mi = ridxB[g * 64 + tid]; }
            }
            // across thetas: strict > (earlier theta wins ties)
            if (mN * bestD[tid] > bestN[tid] * mD) {
                bestN[tid] = mN; bestD[tid] = mD; bestS[tid] = mi; bestT[tid] = t5;
            }
        }
        __syncthreads();                 // merge done before next Phase A overwrites alias
    }

    if (tid < 64) {
        const int o = bx * 64 + tid;     // [half*256 + bt][h]
        outN[o] = bestN[tid];
        outD[o] = bestD[tid];
        outS[o] = bestS[tid];
        outT[o] = bestT[tid];
    }
}

// Kernel 2: merge halves + epilogue. 256 blocks (bt) x 256 threads.
__global__ __launch_bounds__(256) void merge_epilogue(
    const float* __restrict__ x, const float* __restrict__ y,
    const int* __restrict__ mask,
    const float* __restrict__ W1, const float* __restrict__ b1,
    const float* __restrict__ W2, const float* __restrict__ b2,
    const double* __restrict__ N, const double* __restrict__ D,
    const int* __restrict__ S, const int* __restrict__ T,
    float* __restrict__ xf, double* __restrict__ psum, double* __restrict__ pcnt)
{
    __shared__ float  sx[64], sy[64], sh[64], sb1[64], sb2[64];
    __shared__ int    bS[64], bT[64];
    __shared__ double part[4][64], ssum[64], su[64], sred[2][64];

    const int tid = threadIdx.x;
    const int bt  = blockIdx.x;

    if (tid < 64) {
        sx[tid]  = x[bt * 64 + tid];
        sy[tid]  = y[bt * 64 + tid];
        sb1[tid] = b1[tid];
        sb2[tid] = b2[tid];
    }
    __syncthreads();
    if (tid < 64) {
        float acc = 0.0f;
        const float* w1r = W1 + tid * 64;
        for (int i = 0; i < 64; ++i) acc = fmaf(sx[i], w1r[i], acc);
        acc += sb1[tid];
        sh[tid] = acc * (float)mask[bt * 64 + tid];
        // merge: half1 replaces only on strictly greater sim (earlier theta wins ties)
        const int i0 = bt * 64 + tid, i1 = (256 + bt) * 64 + tid;
        const double n0 = N[i0], dd0 = D[i0], n1 = N[i1], dd1 = D[i1];
        if (n1 * dd0 > n0 * dd1) { bS[tid] = S[i1]; bT[tid] = T[i1]; }
        else                     { bS[tid] = S[i0]; bT[tid] = T[i0]; }
    }
    __syncthreads();

    // ssum[i] = sum over h of chosen window value at element i
    {
        const int g = tid >> 6, i = tid & 63;
        double acc = 0.0;
        for (int q = 0; q < 16; ++q) {
            const int h = g * 16 + q;
            const int t5 = bT[h];
            const double theta = (t5 == 4) ? 1.2 : (0.8 + (double)t5 * ((1.2 - 0.8) / 4.0));
            const int L = (int)floor(64.0 * theta);
            const double rcp = 64.0 / (double)L;
            const int j = bS[h] - 63 + i;
            if (j >= 0 && j < L) {
                int sj = (int)floor((double)j * rcp);
                if (sj > 63) sj = 63;
                acc += (double)(sh[h] * W2[sj * 64 + h] + sb2[sj]);
            }
        }
        part[g][i] = acc;
    }
    __syncthreads();
    if (tid < 64) {
        ssum[tid] = part[0][tid] + part[1][tid] + part[2][tid] + part[3][tid];
    }
    __syncthreads();
    if (tid < 64) {
        double u = 64.0 * (double)sb1[tid];
        const float* w1r = W1 + tid * 64;
        for (int i = 0; i < 64; ++i) u += (double)w1r[i] * ssum[i];
        su[tid] = u;
    }
    __syncthreads();
    if (tid < 64) {
        double v = 64.0 * (double)sb2[tid];
        const float* w2r = W2 + tid * 64;
        for (int j = 0; j < 64; ++j) v += (double)w2r[j] * su[j];
        const float outf = (float)v;
        xf[bt * 64 + tid] = outf;
        const float yv = sy[tid];
        double pl = 0.0, pc = 0.0;
        if (yv != 0.0f) {
            const float d = outf - yv;
            pl = (double)(d * d);
            pc = 1.0;
        }
        sred[0][tid] = pl;
        sred[1][tid] = pc;
    }
    __syncthreads();
    if (tid == 0) {
        double a = 0.0, c = 0.0;
        for (int i = 0; i < 64; ++i) { a += sred[0][i]; c += sred[1][i]; }
        psum[bt] = a;
        pcnt[bt] = c;
    }
}

__global__ __launch_bounds__(256) void finalize_loss(
    const double* __restrict__ psum, const double* __restrict__ pcnt,
    float* __restrict__ out)
{
    __shared__ double a[256], c[256];
    const int t = threadIdx.x;
    a[t] = psum[t];
    c[t] = pcnt[t];
    __syncthreads();
    for (int s = 128; s > 0; s >>= 1) {
        if (t < s) { a[t] += a[t + s]; c[t] += c[t + s]; }
        __syncthreads();
    }
    if (t == 0) out[0] = (float)(a[0] / c[0]);
}

extern "C" void kernel_launch(void* const* d_in, const int* in_sizes, int n_in,
                              void* d_out, int out_size, void* d_ws, size_t ws_size,
                              hipStream_t stream) {
    const float* x    = (const float*)d_in[0];
    const float* y    = (const float*)d_in[1];
    const int*   mask = (const int*)d_in[2];
    const float* W1   = (const float*)d_in[3];
    const float* b1   = (const float*)d_in[4];
    const float* W2   = (const float*)d_in[5];
    const float* b2   = (const float*)d_in[6];
    float* out = (float*)d_out;

    char* ws = (char*)d_ws;
    double* Nw   = (double*)(ws);            // 512*64 f64 = 256 KiB
    double* Dw   = (double*)(ws + 262144);   // 256 KiB
    int*    Sw   = (int*)(ws + 524288);      // 128 KiB
    int*    Tw   = (int*)(ws + 655360);      // 128 KiB
    double* psum = (double*)(ws + 786432);
    double* pcnt = (double*)(ws + 788480);

    argaug_scan<<<512, NT, 0, stream>>>(x, y, mask, W1, b1, W2, b2,
                                        Nw, Dw, Sw, Tw);
    merge_epilogue<<<256, 256, 0, stream>>>(x, y, mask, W1, b1, W2, b2,
                                            Nw, Dw, Sw, Tw,
                                            out + 1, psum, pcnt);
    finalize_loss<<<1, 256, 0, stream>>>(psum, pcnt, out);
}

// Round 5
// 62.817 us; speedup vs baseline: 2.6945x; 2.6945x over previous
//
#include <hip/hip_runtime.h>
#include <math.h>

#define NT 512
#define NWAVE 8

// Kernel 1: grid 512 = (bt, theta-half). half0 -> thetas {0,1,2}, half1 -> {3,4}.
// 8 waves; lane = channel hh; wave w owns strips {w, w+8} (9 shifts each) --
// trip(w) + trip(w+8) == L exactly, so waves are perfectly load-balanced.
// Best-sim tracked as (pnum = d*|d|, pden = ss), compared by cross-mult.
__global__ __launch_bounds__(NT) void argaug_scan(
    const float* __restrict__ x, const float* __restrict__ y,
    const int* __restrict__ mask,
    const float* __restrict__ W1, const float* __restrict__ b1,
    const float* __restrict__ W2, const float* __restrict__ b2,
    double* __restrict__ outN, double* __restrict__ outD,
    int* __restrict__ outS, int* __restrict__ outT)
{
    __shared__ double wdBuf[76 * 64];  // f64 window values wd[j][h]; aliased by reduce bufs
    __shared__ double ypad[80];        // ypad[p] = y[p-8] for p in [8,71], else 0
    __shared__ float  sx[64], sy[64], sh[64], sb1[64], sb2[64];
    __shared__ double bestN[64], bestD[64];
    __shared__ int    bestS[64], bestT[64];

    double* rsimN = wdBuf;                         // [8*64] (aliased, barrier-separated)
    double* rsimD = wdBuf + NWAVE * 64;            // [8*64]
    int*    ridxB = (int*)(wdBuf + 2 * NWAVE * 64);

    const int tid  = threadIdx.x;
    const int bx   = blockIdx.x;
    const int bt   = bx & 255;
    const int half = bx >> 8;
    const int hh   = tid & 63;
    const int sg   = tid >> 6;

    if (tid < 64) {
        sx[tid]  = x[bt * 64 + tid];
        sy[tid]  = y[bt * 64 + tid];
        sb1[tid] = b1[tid];
        sb2[tid] = b2[tid];
    }
    __syncthreads();

    if (tid < 64) {
        float acc = 0.0f;
        const float* w1r = W1 + tid * 64;
        for (int i = 0; i < 64; ++i) acc = fmaf(sx[i], w1r[i], acc);
        acc += sb1[tid];
        sh[tid] = acc * (float)mask[bt * 64 + tid];
        bestN[tid] = -1.0; bestD[tid] = 0.0;
        bestS[tid] = 0;    bestT[tid] = 0;
    } else if (tid >= 128 && tid < 208) {
        const int p = tid - 128;
        ypad[p] = (p >= 8 && p < 72) ? (double)sy[p - 8] : 0.0;
    }
    __syncthreads();

    const int t5beg = half ? 3 : 0;
    const int t5end = half ? 5 : 3;

    for (int t5 = t5beg; t5 < t5end; ++t5) {
        const double theta = (t5 == 4) ? 1.2 : (0.8 + (double)t5 * ((1.2 - 0.8) / 4.0));
        const int L = (int)floor(64.0 * theta);   // {51,57,64,70,76}
        const int S = L + 63;
        const double rcp = 64.0 / (double)L;

        // Phase A (parallel): wd[j][h] = (f64)(sh[h]*W2[src(j)][h] + b2[src(j)])
        for (int k = tid; k < L * 64; k += NT) {
            const int j = k >> 6, h = k & 63;     // j wave-uniform
            int sj = (int)floor((double)j * rcp);
            if (sj > 63) sj = 63;
            const float wf = sh[h] * W2[sj * 64 + h] + sb2[sj];
            wdBuf[k] = (double)wf;
        }
        __syncthreads();

        double bN = -1.0, bD = 0.0; int bi = 0x7fffffff;
        #pragma unroll 2
        for (int pp = 0; pp < 2; ++pp) {
            const int s_first = 9 * (sg + 8 * pp);
            if (s_first >= S) continue;
            const int jstart = (s_first > 63) ? (s_first - 63) : 0;
            const int jmid   = (s_first < L - 1) ? s_first : (L - 1);
            const int jend   = (s_first + 8 < L - 1) ? (s_first + 8) : (L - 1);
            const int C      = 71 - s_first;      // ypad idx = j + C - k

            double d0=0,d1=0,d2=0,d3=0,d4=0,d5=0,d6=0,d7=0,d8=0,ssA=0;
            double ym1 = ypad[jstart + C - 1];
            double ym2 = ypad[jstart + C - 2];
            double ym3 = ypad[jstart + C - 3];
            double ym4 = ypad[jstart + C - 4];
            double ym5 = ypad[jstart + C - 5];
            double ym6 = ypad[jstart + C - 6];
            double ym7 = ypad[jstart + C - 7];
            double ym8 = ypad[jstart + C - 8];

            #pragma unroll 9
            for (int j = jstart; j <= jmid; ++j) {
                const double w  = wdBuf[j * 64 + hh];
                const double y0 = ypad[j + C];
                d0 = fma(w, y0,  d0); d1 = fma(w, ym1, d1); d2 = fma(w, ym2, d2);
                d3 = fma(w, ym3, d3); d4 = fma(w, ym4, d4); d5 = fma(w, ym5, d5);
                d6 = fma(w, ym6, d6); d7 = fma(w, ym7, d7); d8 = fma(w, ym8, d8);
                ssA = fma(w, w, ssA);
                ym8=ym7; ym7=ym6; ym6=ym5; ym5=ym4; ym4=ym3; ym3=ym2; ym2=ym1; ym1=y0;
            }
            #pragma unroll 9
            for (int j = jmid + 1; j <= jend; ++j) {
                const double w  = wdBuf[j * 64 + hh];
                const double y0 = ypad[j + C];
                d0 = fma(w, y0,  d0); d1 = fma(w, ym1, d1); d2 = fma(w, ym2, d2);
                d3 = fma(w, ym3, d3); d4 = fma(w, ym4, d4); d5 = fma(w, ym5, d5);
                d6 = fma(w, ym6, d6); d7 = fma(w, ym7, d7); d8 = fma(w, ym8, d8);
                ym8=ym7; ym7=ym6; ym6=ym5; ym5=ym4; ym4=ym3; ym3=ym2; ym2=ym1; ym1=y0;
            }

            const int kmax = (S - s_first < 9) ? (S - s_first) : 9;
            double ss = ssA;
            #define SSUP(kk) { \
                const int jh = s_first + kk; \
                const int jl = s_first + kk - 64; \
                if (jh <= L - 1) { const double w = wdBuf[jh * 64 + hh]; ss = fma(w,  w, ss); } \
                if (jl >= 0)     { const double w = wdBuf[jl * 64 + hh]; ss = fma(-w, w, ss); } }
            #define EVALK(kk, dk) { \
                double pn, pd; \
                if (ss > 0.0) { pn = dk * fabs(dk); pd = ss; } \
                else          { pn = 0.0;           pd = 1.0; } \
                if (pn * bD > bN * pd) { bN = pn; bD = pd; bi = s_first + kk; } }
            EVALK(0, d0)
            if (1 < kmax) { SSUP(1) EVALK(1, d1) }
            if (2 < kmax) { SSUP(2) EVALK(2, d2) }
            if (3 < kmax) { SSUP(3) EVALK(3, d3) }
            if (4 < kmax) { SSUP(4) EVALK(4, d4) }
            if (5 < kmax) { SSUP(5) EVALK(5, d5) }
            if (6 < kmax) { SSUP(6) EVALK(6, d6) }
            if (7 < kmax) { SSUP(7) EVALK(7, d7) }
            if (8 < kmax) { SSUP(8) EVALK(8, d8) }
            #undef SSUP
            #undef EVALK
        }
        __syncthreads();                 // wdBuf reads complete before alias writes
        rsimN[sg * 64 + hh] = bN;
        rsimD[sg * 64 + hh] = bD;
        ridxB[sg * 64 + hh] = bi;
        __syncthreads();
        if (tid < 64) {
            // paired strips interleave s across waves -> explicit tie-break on
            // smaller shift index (exact ties have bitwise-equal (pn,pd)).
            double mN = -1.0, mD = 0.0; int mi = 0x7fffffff;
            for (int g = 0; g < NWAVE; ++g) {
                const double vN = rsimN[g * 64 + tid];
                const double vD = rsimD[g * 64 + tid];
                const int    vi = ridxB[g * 64 + tid];
                const double a = vN * mD, b = mN * vD;
                if (a > b || (a == b && vi < mi)) { mN = vN; mD = vD; mi = vi; }
            }
            // across thetas: strict > (earlier theta wins ties)
            if (mN * bestD[tid] > bestN[tid] * mD) {
                bestN[tid] = mN; bestD[tid] = mD; bestS[tid] = mi; bestT[tid] = t5;
            }
        }
        __syncthreads();                 // merge done before next Phase A overwrites alias
    }

    if (tid < 64) {
        const int o = bx * 64 + tid;     // [half*256 + bt][h]
        outN[o] = bestN[tid];
        outD[o] = bestD[tid];
        outS[o] = bestS[tid];
        outT[o] = bestT[tid];
    }
}

// Kernel 2: merge halves + epilogue. 256 blocks (bt) x 256 threads.
__global__ __launch_bounds__(256) void merge_epilogue(
    const float* __restrict__ x, const float* __restrict__ y,
    const int* __restrict__ mask,
    const float* __restrict__ W1, const float* __restrict__ b1,
    const float* __restrict__ W2, const float* __restrict__ b2,
    const double* __restrict__ N, const double* __restrict__ D,
    const int* __restrict__ S, const int* __restrict__ T,
    float* __restrict__ xf, double* __restrict__ psum, double* __restrict__ pcnt)
{
    __shared__ float  sx[64], sy[64], sh[64], sb1[64], sb2[64];
    __shared__ int    bS[64], bT[64];
    __shared__ double part[4][64], ssum[64], su[64], sred[2][64];

    const int tid = threadIdx.x;
    const int bt  = blockIdx.x;

    if (tid < 64) {
        sx[tid]  = x[bt * 64 + tid];
        sy[tid]  = y[bt * 64 + tid];
        sb1[tid] = b1[tid];
        sb2[tid] = b2[tid];
    }
    __syncthreads();
    if (tid < 64) {
        float acc = 0.0f;
        const float* w1r = W1 + tid * 64;
        for (int i = 0; i < 64; ++i) acc = fmaf(sx[i], w1r[i], acc);
        acc += sb1[tid];
        sh[tid] = acc * (float)mask[bt * 64 + tid];
        // merge: half1 replaces only on strictly greater sim (earlier theta wins ties)
        const int i0 = bt * 64 + tid, i1 = (256 + bt) * 64 + tid;
        const double n0 = N[i0], dd0 = D[i0], n1 = N[i1], dd1 = D[i1];
        if (n1 * dd0 > n0 * dd1) { bS[tid] = S[i1]; bT[tid] = T[i1]; }
        else                     { bS[tid] = S[i0]; bT[tid] = T[i0]; }
    }
    __syncthreads();

    // ssum[i] = sum over h of chosen window value at element i
    {
        const int g = tid >> 6, i = tid & 63;
        double acc = 0.0;
        for (int q = 0; q < 16; ++q) {
            const int h = g * 16 + q;
            const int t5 = bT[h];
            const double theta = (t5 == 4) ? 1.2 : (0.8 + (double)t5 * ((1.2 - 0.8) / 4.0));
            const int L = (int)floor(64.0 * theta);
            const double rcp = 64.0 / (double)L;
            const int j = bS[h] - 63 + i;
            if (j >= 0 && j < L) {
                int sj = (int)floor((double)j * rcp);
                if (sj > 63) sj = 63;
                acc += (double)(sh[h] * W2[sj * 64 + h] + sb2[sj]);
            }
        }
        part[g][i] = acc;
    }
    __syncthreads();
    if (tid < 64) {
        ssum[tid] = part[0][tid] + part[1][tid] + part[2][tid] + part[3][tid];
    }
    __syncthreads();
    if (tid < 64) {
        double u = 64.0 * (double)sb1[tid];
        const float* w1r = W1 + tid * 64;
        for (int i = 0; i < 64; ++i) u += (double)w1r[i] * ssum[i];
        su[tid] = u;
    }
    __syncthreads();
    if (tid < 64) {
        double v = 64.0 * (double)sb2[tid];
        const float* w2r = W2 + tid * 64;
        for (int j = 0; j < 64; ++j) v += (double)w2r[j] * su[j];
        const float outf = (float)v;
        xf[bt * 64 + tid] = outf;
        const float yv = sy[tid];
        double pl = 0.0, pc = 0.0;
        if (yv != 0.0f) {
            const float d = outf - yv;
            pl = (double)(d * d);
            pc = 1.0;
        }
        sred[0][tid] = pl;
        sred[1][tid] = pc;
    }
    __syncthreads();
    if (tid == 0) {
        double a = 0.0, c = 0.0;
        for (int i = 0; i < 64; ++i) { a += sred[0][i]; c += sred[1][i]; }
        psum[bt] = a;
        pcnt[bt] = c;
    }
}

__global__ __launch_bounds__(256) void finalize_loss(
    const double* __restrict__ psum, const double* __restrict__ pcnt,
    float* __restrict__ out)
{
    __shared__ double a[256], c[256];
    const int t = threadIdx.x;
    a[t] = psum[t];
    c[t] = pcnt[t];
    __syncthreads();
    for (int s = 128; s > 0; s >>= 1) {
        if (t < s) { a[t] += a[t + s]; c[t] += c[t + s]; }
        __syncthreads();
    }
    if (t == 0) out[0] = (float)(a[0] / c[0]);
}

extern "C" void kernel_launch(void* const* d_in, const int* in_sizes, int n_in,
                              void* d_out, int out_size, void* d_ws, size_t ws_size,
                              hipStream_t stream) {
    const float* x    = (const float*)d_in[0];
    const float* y    = (const float*)d_in[1];
    const int*   mask = (const int*)d_in[2];
    const float* W1   = (const float*)d_in[3];
    const float* b1   = (const float*)d_in[4];
    const float* W2   = (const float*)d_in[5];
    const float* b2   = (const float*)d_in[6];
    float* out = (float*)d_out;

    char* ws = (char*)d_ws;
    double* Nw   = (double*)(ws);            // 512*64 f64 = 256 KiB
    double* Dw   = (double*)(ws + 262144);   // 256 KiB
    int*    Sw   = (int*)(ws + 524288);      // 128 KiB
    int*    Tw   = (int*)(ws + 655360);      // 128 KiB
    double* psum = (double*)(ws + 786432);
    double* pcnt = (double*)(ws + 788480);

    argaug_scan<<<512, NT, 0, stream>>>(x, y, mask, W1, b1, W2, b2,
                                        Nw, Dw, Sw, Tw);
    merge_epilogue<<<256, 256, 0, stream>>>(x, y, mask, W1, b1, W2, b2,
                                            Nw, Dw, Sw, Tw,
                                            out + 1, psum, pcnt);
    finalize_loss<<<1, 256, 0, stream>>>(psum, pcnt, out);
}

// Round 6
// 51.777 us; speedup vs baseline: 3.2691x; 1.2132x over previous
//
#include <hip/hip_runtime.h>
#include <math.h>

#define NT 512
#define NWAVE 8

// Kernel 1: grid 1280 = (theta t5 = bx>>8) x (bt = bx&255). 8 waves; lane =
// channel hh; wave w owns strips {w, w+8} (9 shifts each): span(w)+span(w+8)
// == L exactly -> perfect balance. Window values computed on the fly from
// sW2 (LDS) + per-j {src*64, b2bits} table; widened f32->f64 at use, which is
// bitwise-identical to the previous wdBuf path. Best-sim tracked as
// (pnum = d*|d|, pden = ss), compared by cross-multiplication.
__global__ __launch_bounds__(NT) void argaug_scan(
    const float* __restrict__ x, const float* __restrict__ y,
    const int* __restrict__ mask,
    const float* __restrict__ W1, const float* __restrict__ b1,
    const float* __restrict__ W2, const float* __restrict__ b2,
    double* __restrict__ outN, double* __restrict__ outD, int* __restrict__ outS)
{
    __shared__ float  sW2[4096];        // W2[o][h] row-major (16 KB)
    __shared__ double ypad[80];         // ypad[p] = y[p-8] for p in [8,71], else 0
    __shared__ float  sx[64], sh[64], sb1[64];
    __shared__ int2   ssrc[80];         // {src*64, bits(b2[src])} per j
    __shared__ double rsimN[NWAVE * 64], rsimD[NWAVE * 64];
    __shared__ int    ridxB[NWAVE * 64];

    const int tid = threadIdx.x;
    const int bx  = blockIdx.x;
    const int bt  = bx & 255;
    const int t5  = bx >> 8;
    const int hh  = tid & 63;
    const int sg  = tid >> 6;

    const double theta = (t5 == 4) ? 1.2 : (0.8 + (double)t5 * ((1.2 - 0.8) / 4.0));
    const int L = (int)floor(64.0 * theta);   // {51,57,64,70,76}
    const int S = L + 63;
    const double rcp = 64.0 / (double)L;

    for (int k = tid; k < 4096; k += NT) sW2[k] = W2[k];
    if (tid < 64) {
        sx[tid]  = x[bt * 64 + tid];
        sb1[tid] = b1[tid];
    } else if (tid >= 128 && tid < 208) {
        const int p = tid - 128;
        ypad[p] = (p >= 8 && p < 72) ? (double)y[bt * 64 + p - 8] : 0.0;
    } else if (tid >= 256 && tid < 256 + L) {
        const int j = tid - 256;
        int sj = (int)floor((double)j * rcp);
        if (sj > 63) sj = 63;
        ssrc[j] = make_int2(sj * 64, __float_as_int(b2[sj]));
    }
    __syncthreads();

    if (tid < 64) {
        float acc = 0.0f;
        const float* w1r = W1 + tid * 64;
        for (int i = 0; i < 64; ++i) acc = fmaf(sx[i], w1r[i], acc);
        acc += sb1[tid];
        sh[tid] = acc * (float)mask[bt * 64 + tid];
    }
    __syncthreads();

    const float shv = sh[hh];

    double bN = -1.0, bD = 0.0; int bi = 0x7fffffff;
    #pragma unroll 2
    for (int pp = 0; pp < 2; ++pp) {
        const int s_first = 9 * (sg + 8 * pp);
        if (s_first >= S) continue;
        const int jstart = (s_first > 63) ? (s_first - 63) : 0;
        const int jmid   = (s_first < L - 1) ? s_first : (L - 1);
        const int jend   = (s_first + 8 < L - 1) ? (s_first + 8) : (L - 1);
        const int C      = 71 - s_first;      // ypad idx = j + C - k

        double d0=0,d1=0,d2=0,d3=0,d4=0,d5=0,d6=0,d7=0,d8=0,ssA=0;
        double ym1 = ypad[jstart + C - 1];
        double ym2 = ypad[jstart + C - 2];
        double ym3 = ypad[jstart + C - 3];
        double ym4 = ypad[jstart + C - 4];
        double ym5 = ypad[jstart + C - 5];
        double ym6 = ypad[jstart + C - 6];
        double ym7 = ypad[jstart + C - 7];
        double ym8 = ypad[jstart + C - 8];

        #pragma unroll 9
        for (int j = jstart; j <= jmid; ++j) {
            const int2 ow = ssrc[j];
            const double w  = (double)fmaf(shv, sW2[ow.x + hh], __int_as_float(ow.y));
            const double y0 = ypad[j + C];
            d0 = fma(w, y0,  d0); d1 = fma(w, ym1, d1); d2 = fma(w, ym2, d2);
            d3 = fma(w, ym3, d3); d4 = fma(w, ym4, d4); d5 = fma(w, ym5, d5);
            d6 = fma(w, ym6, d6); d7 = fma(w, ym7, d7); d8 = fma(w, ym8, d8);
            ssA = fma(w, w, ssA);
            ym8=ym7; ym7=ym6; ym6=ym5; ym5=ym4; ym4=ym3; ym3=ym2; ym2=ym1; ym1=y0;
        }
        #pragma unroll 9
        for (int j = jmid + 1; j <= jend; ++j) {
            const int2 ow = ssrc[j];
            const double w  = (double)fmaf(shv, sW2[ow.x + hh], __int_as_float(ow.y));
            const double y0 = ypad[j + C];
            d0 = fma(w, y0,  d0); d1 = fma(w, ym1, d1); d2 = fma(w, ym2, d2);
            d3 = fma(w, ym3, d3); d4 = fma(w, ym4, d4); d5 = fma(w, ym5, d5);
            d6 = fma(w, ym6, d6); d7 = fma(w, ym7, d7); d8 = fma(w, ym8, d8);
            ym8=ym7; ym7=ym6; ym6=ym5; ym5=ym4; ym4=ym3; ym3=ym2; ym2=ym1; ym1=y0;
        }

        const int kmax = (S - s_first < 9) ? (S - s_first) : 9;
        double ss = ssA;
        #define SSUP(kk) { \
            const int jh = s_first + kk; \
            const int jl = jh - 64; \
            if (jh <= L - 1) { const int2 ow = ssrc[jh]; \
                const double w = (double)fmaf(shv, sW2[ow.x + hh], __int_as_float(ow.y)); \
                ss = fma(w,  w, ss); } \
            if (jl >= 0) { const int2 ow = ssrc[jl]; \
                const double w = (double)fmaf(shv, sW2[ow.x + hh], __int_as_float(ow.y)); \
                ss = fma(-w, w, ss); } }
        #define EVALK(kk, dk) { \
            double pn, pd; \
            if (ss > 0.0) { pn = dk * fabs(dk); pd = ss; } \
            else          { pn = 0.0;           pd = 1.0; } \
            if (pn * bD > bN * pd) { bN = pn; bD = pd; bi = s_first + kk; } }
        EVALK(0, d0)
        if (1 < kmax) { SSUP(1) EVALK(1, d1) }
        if (2 < kmax) { SSUP(2) EVALK(2, d2) }
        if (3 < kmax) { SSUP(3) EVALK(3, d3) }
        if (4 < kmax) { SSUP(4) EVALK(4, d4) }
        if (5 < kmax) { SSUP(5) EVALK(5, d5) }
        if (6 < kmax) { SSUP(6) EVALK(6, d6) }
        if (7 < kmax) { SSUP(7) EVALK(7, d7) }
        if (8 < kmax) { SSUP(8) EVALK(8, d8) }
        #undef SSUP
        #undef EVALK
    }

    rsimN[sg * 64 + hh] = bN;
    rsimD[sg * 64 + hh] = bD;
    ridxB[sg * 64 + hh] = bi;
    __syncthreads();
    if (tid < 64) {
        // waves interleave s-order -> explicit tie-break on smaller shift index
        // (exact ties have bitwise-equal (pn,pd) pairs).
        double mN = -1.0, mD = 0.0; int mi = 0x7fffffff;
        for (int g = 0; g < NWAVE; ++g) {
            const double vN = rsimN[g * 64 + tid];
            const double vD = rsimD[g * 64 + tid];
            const int    vi = ridxB[g * 64 + tid];
            const double a = vN * mD, b = mN * vD;
            if (a > b || (a == b && vi < mi)) { mN = vN; mD = vD; mi = vi; }
        }
        const int o = bx * 64 + tid;     // [t5*256 + bt][h]
        outN[o] = mN;
        outD[o] = mD;
        outS[o] = mi;
    }
}

// Kernel 2: merge 5 thetas + epilogue. 256 blocks (bt) x 256 threads.
__global__ __launch_bounds__(256) void merge_epilogue(
    const float* __restrict__ x, const float* __restrict__ y,
    const int* __restrict__ mask,
    const float* __restrict__ W1, const float* __restrict__ b1,
    const float* __restrict__ W2, const float* __restrict__ b2,
    const double* __restrict__ N, const double* __restrict__ D,
    const int* __restrict__ S,
    float* __restrict__ xf, double* __restrict__ psum, double* __restrict__ pcnt)
{
    __shared__ float  sx[64], sy[64], sh[64], sb1[64], sb2[64];
    __shared__ int    bS[64], bT[64];
    __shared__ double part[4][64], ssum[64], su[64], sred[2][64];

    const int tid = threadIdx.x;
    const int bt  = blockIdx.x;

    if (tid < 64) {
        sx[tid]  = x[bt * 64 + tid];
        sy[tid]  = y[bt * 64 + tid];
        sb1[tid] = b1[tid];
        sb2[tid] = b2[tid];
    }
    __syncthreads();
    if (tid < 64) {
        float acc = 0.0f;
        const float* w1r = W1 + tid * 64;
        for (int i = 0; i < 64; ++i) acc = fmaf(sx[i], w1r[i], acc);
        acc += sb1[tid];
        sh[tid] = acc * (float)mask[bt * 64 + tid];
        // merge across thetas: ascending t5, strictly greater wins (earlier
        // theta keeps exact ties, matching the reference update rule).
        double mN = -1.0, mD = 0.0; int mS = 0, mT = 0;
        for (int t5 = 0; t5 < 5; ++t5) {
            const int i = (t5 * 256 + bt) * 64 + tid;
            const double vN = N[i], vD = D[i];
            if (vN * mD > mN * vD) { mN = vN; mD = vD; mS = S[i]; mT = t5; }
        }
        bS[tid] = mS; bT[tid] = mT;
    }
    __syncthreads();

    // ssum[i] = sum over h of chosen window value at element i
    {
        const int g = tid >> 6, i = tid & 63;
        double acc = 0.0;
        for (int q = 0; q < 16; ++q) {
            const int h = g * 16 + q;
            const int t5 = bT[h];
            const double theta = (t5 == 4) ? 1.2 : (0.8 + (double)t5 * ((1.2 - 0.8) / 4.0));
            const int L = (int)floor(64.0 * theta);
            const double rcp = 64.0 / (double)L;
            const int j = bS[h] - 63 + i;
            if (j >= 0 && j < L) {
                int sj = (int)floor((double)j * rcp);
                if (sj > 63) sj = 63;
                acc += (double)(sh[h] * W2[sj * 64 + h] + sb2[sj]);
            }
        }
        part[g][i] = acc;
    }
    __syncthreads();
    if (tid < 64) {
        ssum[tid] = part[0][tid] + part[1][tid] + part[2][tid] + part[3][tid];
    }
    __syncthreads();
    if (tid < 64) {
        double u = 64.0 * (double)sb1[tid];
        const float* w1r = W1 + tid * 64;
        for (int i = 0; i < 64; ++i) u += (double)w1r[i] * ssum[i];
        su[tid] = u;
    }
    __syncthreads();
    if (tid < 64) {
        double v = 64.0 * (double)sb2[tid];
        const float* w2r = W2 + tid * 64;
        for (int j = 0; j < 64; ++j) v += (double)w2r[j] * su[j];
        const float outf = (float)v;
        xf[bt * 64 + tid] = outf;
        const float yv = sy[tid];
        double pl = 0.0, pc = 0.0;
        if (yv != 0.0f) {
            const float d = outf - yv;
            pl = (double)(d * d);
            pc = 1.0;
        }
        sred[0][tid] = pl;
        sred[1][tid] = pc;
    }
    __syncthreads();
    if (tid == 0) {
        double a = 0.0, c = 0.0;
        for (int i = 0; i < 64; ++i) { a += sred[0][i]; c += sred[1][i]; }
        psum[bt] = a;
        pcnt[bt] = c;
    }
}

__global__ __launch_bounds__(256) void finalize_loss(
    const double* __restrict__ psum, const double* __restrict__ pcnt,
    float* __restrict__ out)
{
    __shared__ double a[256], c[256];
    const int t = threadIdx.x;
    a[t] = psum[t];
    c[t] = pcnt[t];
    __syncthreads();
    for (int s = 128; s > 0; s >>= 1) {
        if (t < s) { a[t] += a[t + s]; c[t] += c[t + s]; }
        __syncthreads();
    }
    if (t == 0) out[0] = (float)(a[0] / c[0]);
}

extern "C" void kernel_launch(void* const* d_in, const int* in_sizes, int n_in,
                              void* d_out, int out_size, void* d_ws, size_t ws_size,
                              hipStream_t stream) {
    const float* x    = (const float*)d_in[0];
    const float* y    = (const float*)d_in[1];
    const int*   mask = (const int*)d_in[2];
    const float* W1   = (const float*)d_in[3];
    const float* b1   = (const float*)d_in[4];
    const float* W2   = (const float*)d_in[5];
    const float* b2   = (const float*)d_in[6];
    float* out = (float*)d_out;

    char* ws = (char*)d_ws;
    double* Nw   = (double*)(ws);             // 5*256*64 f64 = 640 KiB
    double* Dw   = (double*)(ws + 655360);    // 640 KiB
    int*    Sw   = (int*)(ws + 1310720);      // 320 KiB
    double* psum = (double*)(ws + 1638400);
    double* pcnt = (double*)(ws + 1640448);

    argaug_scan<<<1280, NT, 0, stream>>>(x, y, mask, W1, b1, W2, b2,
                                         Nw, Dw, Sw);
    merge_epilogue<<<256, 256, 0, stream>>>(x, y, mask, W1, b1, W2, b2,
                                            Nw, Dw, Sw,
                                            out + 1, psum, pcnt);
    finalize_loss<<<1, 256, 0, stream>>>(psum, pcnt, out);
}

// Round 7
// 49.804 us; speedup vs baseline: 3.3986x; 1.0396x over previous
//
#include <hip/hip_runtime.h>
#include <math.h>

#define NT 512
#define NWAVE 8

// Kernel 1: grid 1280 = (theta t5 = bx>>8) x (bt = bx&255). 8 waves; lane =
// channel hh; wave w owns strips {w, w+8} (9 shifts each): span(w)+span(w+8)
// == L exactly -> perfect balance. Window values materialized ONCE per block
// as f64 in LDS (wdBuf) -- bitwise identical to computing on the fly -- so the
// hot loop is 2 LDS reads + 10 f64 FMA per element. Best-sim tracked as
// (pnum = d*|d|, pden = ss), compared by cross-multiplication.
__global__ __launch_bounds__(NT) void argaug_scan(
    const float* __restrict__ x, const float* __restrict__ y,
    const int* __restrict__ mask,
    const float* __restrict__ W1, const float* __restrict__ b1,
    const float* __restrict__ W2, const float* __restrict__ b2,
    double* __restrict__ outN, double* __restrict__ outD, int* __restrict__ outS)
{
    __shared__ double wdBuf[76 * 64];   // 38912 B; aliased by reduce bufs at the end
    __shared__ double ypad[80];         // ypad[p] = y[p-8] for p in [8,71], else 0
    __shared__ float  sx[64], sh[64], sb1[64];

    double* rsimN = wdBuf;                         // aliased, barrier-separated
    double* rsimD = wdBuf + NWAVE * 64;
    int*    ridxB = (int*)(wdBuf + 2 * NWAVE * 64);

    const int tid = threadIdx.x;
    const int bx  = blockIdx.x;
    const int bt  = bx & 255;
    const int t5  = bx >> 8;
    const int hh  = tid & 63;
    const int sg  = tid >> 6;

    const double theta = (t5 == 4) ? 1.2 : (0.8 + (double)t5 * ((1.2 - 0.8) / 4.0));
    const int L = (int)floor(64.0 * theta);   // {51,57,64,70,76}
    const int S = L + 63;
    const double rcp = 64.0 / (double)L;

    if (tid < 64) {
        sx[tid]  = x[bt * 64 + tid];
        sb1[tid] = b1[tid];
    } else if (tid >= 128 && tid < 208) {
        const int p = tid - 128;
        ypad[p] = (p >= 8 && p < 72) ? (double)y[bt * 64 + p - 8] : 0.0;
    }
    __syncthreads();

    if (tid < 64) {
        float acc = 0.0f;
        const float* w1r = W1 + tid * 64;
        for (int i = 0; i < 64; ++i) acc = fmaf(sx[i], w1r[i], acc);
        acc += sb1[tid];
        sh[tid] = acc * (float)mask[bt * 64 + tid];
    }
    __syncthreads();

    // Phase A: wd[j][h] = (f64)(sh[h]*W2[src(j)][h] + b2[src(j)]); W2 via L2.
    for (int k = tid; k < L * 64; k += NT) {
        const int j = k >> 6, h = k & 63;     // j wave-uniform
        int sj = (int)floor((double)j * rcp);
        if (sj > 63) sj = 63;
        const float wf = fmaf(sh[h], W2[sj * 64 + h], b2[sj]);
        wdBuf[k] = (double)wf;
    }
    __syncthreads();

    double bN = -1.0, bD = 0.0; int bi = 0x7fffffff;
    #pragma unroll 2
    for (int pp = 0; pp < 2; ++pp) {
        const int s_first = 9 * (sg + 8 * pp);
        if (s_first >= S) continue;
        const int jstart = (s_first > 63) ? (s_first - 63) : 0;
        const int jmid   = (s_first < L - 1) ? s_first : (L - 1);
        const int jend   = (s_first + 8 < L - 1) ? (s_first + 8) : (L - 1);
        const int C      = 71 - s_first;      // ypad idx = j + C - k

        double d0=0,d1=0,d2=0,d3=0,d4=0,d5=0,d6=0,d7=0,d8=0,ssA=0;
        double ym1 = ypad[jstart + C - 1];
        double ym2 = ypad[jstart + C - 2];
        double ym3 = ypad[jstart + C - 3];
        double ym4 = ypad[jstart + C - 4];
        double ym5 = ypad[jstart + C - 5];
        double ym6 = ypad[jstart + C - 6];
        double ym7 = ypad[jstart + C - 7];
        double ym8 = ypad[jstart + C - 8];

        #pragma unroll 9
        for (int j = jstart; j <= jmid; ++j) {
            const double w  = wdBuf[j * 64 + hh];
            const double y0 = ypad[j + C];
            d0 = fma(w, y0,  d0); d1 = fma(w, ym1, d1); d2 = fma(w, ym2, d2);
            d3 = fma(w, ym3, d3); d4 = fma(w, ym4, d4); d5 = fma(w, ym5, d5);
            d6 = fma(w, ym6, d6); d7 = fma(w, ym7, d7); d8 = fma(w, ym8, d8);
            ssA = fma(w, w, ssA);
            ym8=ym7; ym7=ym6; ym6=ym5; ym5=ym4; ym4=ym3; ym3=ym2; ym2=ym1; ym1=y0;
        }
        #pragma unroll 9
        for (int j = jmid + 1; j <= jend; ++j) {
            const double w  = wdBuf[j * 64 + hh];
            const double y0 = ypad[j + C];
            d0 = fma(w, y0,  d0); d1 = fma(w, ym1, d1); d2 = fma(w, ym2, d2);
            d3 = fma(w, ym3, d3); d4 = fma(w, ym4, d4); d5 = fma(w, ym5, d5);
            d6 = fma(w, ym6, d6); d7 = fma(w, ym7, d7); d8 = fma(w, ym8, d8);
            ym8=ym7; ym7=ym6; ym6=ym5; ym5=ym4; ym4=ym3; ym3=ym2; ym2=ym1; ym1=y0;
        }

        const int kmax = (S - s_first < 9) ? (S - s_first) : 9;
        double ss = ssA;
        #define SSUP(kk) { \
            const int jh = s_first + kk; \
            const int jl = jh - 64; \
            if (jh <= L - 1) { const double w = wdBuf[jh * 64 + hh]; ss = fma(w,  w, ss); } \
            if (jl >= 0)     { const double w = wdBuf[jl * 64 + hh]; ss = fma(-w, w, ss); } }
        #define EVALK(kk, dk) { \
            double pn, pd; \
            if (ss > 0.0) { pn = dk * fabs(dk); pd = ss; } \
            else          { pn = 0.0;           pd = 1.0; } \
            if (pn * bD > bN * pd) { bN = pn; bD = pd; bi = s_first + kk; } }
        EVALK(0, d0)
        if (1 < kmax) { SSUP(1) EVALK(1, d1) }
        if (2 < kmax) { SSUP(2) EVALK(2, d2) }
        if (3 < kmax) { SSUP(3) EVALK(3, d3) }
        if (4 < kmax) { SSUP(4) EVALK(4, d4) }
        if (5 < kmax) { SSUP(5) EVALK(5, d5) }
        if (6 < kmax) { SSUP(6) EVALK(6, d6) }
        if (7 < kmax) { SSUP(7) EVALK(7, d7) }
        if (8 < kmax) { SSUP(8) EVALK(8, d8) }
        #undef SSUP
        #undef EVALK
    }

    __syncthreads();                 // all wdBuf reads complete before alias writes
    rsimN[sg * 64 + hh] = bN;
    rsimD[sg * 64 + hh] = bD;
    ridxB[sg * 64 + hh] = bi;
    __syncthreads();
    if (tid < 64) {
        // waves interleave s-order -> explicit tie-break on smaller shift index
        // (exact ties have bitwise-equal (pn,pd) pairs).
        double mN = -1.0, mD = 0.0; int mi = 0x7fffffff;
        for (int g = 0; g < NWAVE; ++g) {
            const double vN = rsimN[g * 64 + tid];
            const double vD = rsimD[g * 64 + tid];
            const int    vi = ridxB[g * 64 + tid];
            const double a = vN * mD, b = mN * vD;
            if (a > b || (a == b && vi < mi)) { mN = vN; mD = vD; mi = vi; }
        }
        const int o = bx * 64 + tid;     // [t5*256 + bt][h]
        outN[o] = mN;
        outD[o] = mD;
        outS[o] = mi;
    }
}

// Kernel 2: merge 5 thetas + epilogue. 256 blocks (bt) x 256 threads.
__global__ __launch_bounds__(256) void merge_epilogue(
    const float* __restrict__ x, const float* __restrict__ y,
    const int* __restrict__ mask,
    const float* __restrict__ W1, const float* __restrict__ b1,
    const float* __restrict__ W2, const float* __restrict__ b2,
    const double* __restrict__ N, const double* __restrict__ D,
    const int* __restrict__ S,
    float* __restrict__ xf, double* __restrict__ psum, double* __restrict__ pcnt)
{
    __shared__ float  sx[64], sy[64], sh[64];
    __shared__ int    bS[64], bT[64];
    __shared__ double part[4][64], ssum[64], su[64];

    const int tid = threadIdx.x;
    const int bt  = blockIdx.x;
    const int g   = tid >> 6, i = tid & 63;

    if (tid < 64) {
        sx[tid] = x[bt * 64 + tid];
        sy[tid] = y[bt * 64 + tid];
    }
    __syncthreads();
    if (tid < 64) {
        // fc1 serial fmaf chain: bitwise-identical to kernel 1's sh
        float acc = 0.0f;
        const float* w1r = W1 + tid * 64;
        for (int k = 0; k < 64; ++k) acc = fmaf(sx[k], w1r[k], acc);
        acc += b1[tid];
        sh[tid] = acc * (float)mask[bt * 64 + tid];
        // merge across thetas: ascending t5, strictly greater wins (earlier
        // theta keeps exact ties, matching the reference update rule).
        double mN = -1.0, mD = 0.0; int mS = 0, mT = 0;
        for (int t5 = 0; t5 < 5; ++t5) {
            const int o = (t5 * 256 + bt) * 64 + tid;
            const double vN = N[o], vD = D[o];
            if (vN * mD > mN * vD) { mN = vN; mD = vD; mS = S[o]; mT = t5; }
        }
        bS[tid] = mS; bT[tid] = mT;
    }
    __syncthreads();

    // ssum[i] = sum over h of chosen window value at element i (4-way over h)
    {
        double acc = 0.0;
        for (int q = 0; q < 16; ++q) {
            const int h = g * 16 + q;
            const int t5 = bT[h];
            const double theta = (t5 == 4) ? 1.2 : (0.8 + (double)t5 * ((1.2 - 0.8) / 4.0));
            const int L = (int)floor(64.0 * theta);
            const double rcp = 64.0 / (double)L;
            const int j = bS[h] - 63 + i;
            if (j >= 0 && j < L) {
                int sj = (int)floor((double)j * rcp);
                if (sj > 63) sj = 63;
                acc += (double)fmaf(sh[h], W2[sj * 64 + h], b2[sj]);
            }
        }
        part[g][i] = acc;
    }
    __syncthreads();
    if (tid < 64) {
        ssum[tid] = part[0][tid] + part[1][tid] + part[2][tid] + part[3][tid];
    }
    __syncthreads();
    // u = W1 * ssum + 64*b1 (4-way partial over inner dim)
    {
        double acc = 0.0;
        const int base = g * 16;
        for (int q = 0; q < 16; ++q)
            acc += (double)W1[i * 64 + base + q] * ssum[base + q];
        part[g][i] = acc;
    }
    __syncthreads();
    if (tid < 64) {
        su[tid] = 64.0 * (double)b1[tid]
                + part[0][tid] + part[1][tid] + part[2][tid] + part[3][tid];
    }
    __syncthreads();
    // out = W2 * u + 64*b2 (4-way partial over inner dim)
    {
        double acc = 0.0;
        const int base = g * 16;
        for (int q = 0; q < 16; ++q)
            acc += (double)W2[i * 64 + base + q] * su[base + q];
        part[g][i] = acc;
    }
    __syncthreads();
    if (tid < 64) {
        const double v = 64.0 * (double)b2[tid]
                       + part[0][tid] + part[1][tid] + part[2][tid] + part[3][tid];
        const float outf = (float)v;
        xf[bt * 64 + tid] = outf;
        const float yv = sy[tid];
        double pl = 0.0, pc = 0.0;
        if (yv != 0.0f) {
            const float d = outf - yv;
            pl = (double)(d * d);
            pc = 1.0;
        }
        for (int o = 32; o > 0; o >>= 1) {
            pl += __shfl_down(pl, o, 64);
            pc += __shfl_down(pc, o, 64);
        }
        if (tid == 0) { psum[bt] = pl; pcnt[bt] = pc; }
    }
}

__global__ __launch_bounds__(256) void finalize_loss(
    const double* __restrict__ psum, const double* __restrict__ pcnt,
    float* __restrict__ out)
{
    __shared__ double a[256], c[256];
    const int t = threadIdx.x;
    a[t] = psum[t];
    c[t] = pcnt[t];
    __syncthreads();
    for (int s = 128; s > 0; s >>= 1) {
        if (t < s) { a[t] += a[t + s]; c[t] += c[t + s]; }
        __syncthreads();
    }
    if (t == 0) out[0] = (float)(a[0] / c[0]);
}

extern "C" void kernel_launch(void* const* d_in, const int* in_sizes, int n_in,
                              void* d_out, int out_size, void* d_ws, size_t ws_size,
                              hipStream_t stream) {
    const float* x    = (const float*)d_in[0];
    const float* y    = (const float*)d_in[1];
    const int*   mask = (const int*)d_in[2];
    const float* W1   = (const float*)d_in[3];
    const float* b1   = (const float*)d_in[4];
    const float* W2   = (const float*)d_in[5];
    const float* b2   = (const float*)d_in[6];
    float* out = (float*)d_out;

    char* ws = (char*)d_ws;
    double* Nw   = (double*)(ws);             // 5*256*64 f64 = 640 KiB
    double* Dw   = (double*)(ws + 655360);    // 640 KiB
    int*    Sw   = (int*)(ws + 1310720);      // 320 KiB
    double* psum = (double*)(ws + 1638400);
    double* pcnt = (double*)(ws + 1640448);

    argaug_scan<<<1280, NT, 0, stream>>>(x, y, mask, W1, b1, W2, b2,
                                         Nw, Dw, Sw);
    merge_epilogue<<<256, 256, 0, stream>>>(x, y, mask, W1, b1, W2, b2,
                                            Nw, Dw, Sw,
                                            out + 1, psum, pcnt);
    finalize_loss<<<1, 256, 0, stream>>>(psum, pcnt, out);
}